// Round 6
// baseline (218.571 us; speedup 1.0000x reference)
//
#include <hip/hip_runtime.h>

// x[1,32,14,14,14] -> trilinear upsample(224, align_corners) -> 1x1x1 conv
// (32->4) -> softmax(dim=1). Output [1,4,224,224,224] fp32.
//
// Conv commutes with linear interp -> contract 32->4 on the 14^3 grid (k1).
// R6: FILL-SHAPED STORE KERNEL. R0-R5 pinned the store path at 2.1-2.5 TB/s
// while fillBufferAligned does 6.6 TB/s on the same buffer. Remaining
// structural difference: fill = continuous, single-stream-per-wave monotone
// stores from lean 256-thread blocks. Replicate exactly that: each block
// owns 8 KB contiguous of ONE channel (c = blockIdx/5488, block-uniform),
// recomputes the 4-channel softmax inline (redundancy 4x, ~22 us chip-wide,
// hides under stores), stores only its channel: out + gid*8, 2 KB contiguous
// per wave-instruction, no LDS, no barriers, no interleave, no bursts.
// z table (44 KB) stays in L1/L2; lanes' scattered reads merge (<=3 lines).

#define NSP 2744             // 14^3
#define NPLANE 196           // 14*14
#define NV 11239424u         // 224^3
#define GPC 1404928u         // NV/8: 8-voxel groups per channel
#define RATIO (13.0f / 223.0f)
#define LOG2E 1.44269504088896340736f

// ---------------- Kernel 1: z[s] = LOG2E*(W @ x + b) on the 14^3 grid ------
__global__ __launch_bounds__(256) void conv_small(
    const float* __restrict__ x,   // [32][2744]
    const float* __restrict__ W,   // [4][32]
    const float* __restrict__ b,   // [4]
    float4* __restrict__ z)        // [2744]
{
    int s = blockIdx.x * 256 + threadIdx.x;
    if (s >= NSP) return;
    float a0 = b[0], a1 = b[1], a2 = b[2], a3 = b[3];
#pragma unroll
    for (int c = 0; c < 32; ++c) {
        float xv = x[c * NSP + s];
        a0 = fmaf(W[c],      xv, a0);
        a1 = fmaf(W[32 + c], xv, a1);
        a2 = fmaf(W[64 + c], xv, a2);
        a3 = fmaf(W[96 + c], xv, a3);
    }
    // fold log2(e): softmax computed in exp2 domain downstream
    z[s] = make_float4(a0 * LOG2E, a1 * LOG2E, a2 * LOG2E, a3 * LOG2E);
}

__device__ __forceinline__ float4 bilerp4(const float4* __restrict__ zs,
                                          int b00, int iw,
                                          float c00, float c01, float c10, float c11)
{
    float4 A = zs[b00 + iw], B = zs[b00 + 14 + iw];
    float4 C = zs[b00 + 196 + iw], D = zs[b00 + 210 + iw];
    float4 r;
    r.x = fmaf(c11, D.x, fmaf(c10, C.x, fmaf(c01, B.x, c00 * A.x)));
    r.y = fmaf(c11, D.y, fmaf(c10, C.y, fmaf(c01, B.y, c00 * A.y)));
    r.z = fmaf(c11, D.z, fmaf(c10, C.z, fmaf(c01, B.z, c00 * A.z)));
    r.w = fmaf(c11, D.w, fmaf(c10, C.w, fmaf(c01, B.w, c00 * A.w)));
    return r;
}

// ---------------- Kernel 2: fill-shaped upsample+softmax store -------------
// grid 21952 x 256: gid in [0, 4*NV/8); each thread -> 8 consecutive voxels
// of channel gid/GPC; output floats at out + gid*8 (fully linear coverage).
__global__ __launch_bounds__(256) void store_stream(
    const float4* __restrict__ z,  // [14][14][14]
    float* __restrict__ out)       // [4][224][224][224]
{
    unsigned gid = blockIdx.x * 256u + threadIdx.x;
    unsigned c   = gid / GPC;              // block-uniform (GPC/256 = 5488)
    unsigned rem = gid - c * GPC;
    unsigned row = rem / 28u;              // d*224 + h
    unsigned w8  = (rem - row * 28u) * 8u; // starting w (8 | 224: no straddle)
    unsigned hh  = row % 224u;
    unsigned dd  = row / 224u;

    float posd = (float)dd * RATIO;
    int   i0d  = min((int)posd, 12);
    float wd   = posd - (float)i0d;
    float posh = (float)hh * RATIO;
    int   i0h  = min((int)posh, 12);
    float wh   = posh - (float)i0h;

    float c11 = wd * wh;
    float c10 = wd - c11;
    float c01 = wh - c11;
    float c00 = 1.0f - wd - wh + c11;

    float posw0 = (float)w8 * RATIO;       // <= 12.59 -> iw0 <= 12
    int   iw0   = min((int)posw0, 12);
    float u     = posw0 - (float)iw0;      // u_j = u + j*RATIO < 1.42

    int b00 = (i0d * 14 + i0h) * 14;
    float4 g0 = bilerp4(z, b00, iw0,              c00, c01, c10, c11);
    float4 g1 = bilerp4(z, b00, iw0 + 1,          c00, c01, c10, c11);
    float4 g2 = bilerp4(z, b00, min(iw0 + 2, 13), c00, c01, c10, c11);

    float4 d10, d21;
    d10.x = g1.x - g0.x; d10.y = g1.y - g0.y; d10.z = g1.z - g0.z; d10.w = g1.w - g0.w;
    d21.x = g2.x - g1.x; d21.y = g2.y - g1.y; d21.z = g2.z - g1.z; d21.w = g2.w - g1.w;

    float r[8];
#pragma unroll
    for (int j = 0; j < 8; ++j) {
        // piecewise-linear in u: val = g0 + min(u,1)*d10 + max(u-1,0)*d21
        float a  = fminf(u, 1.0f);
        float bb = u - a;
        float t0 = fmaf(bb, d21.x, fmaf(a, d10.x, g0.x));
        float t1 = fmaf(bb, d21.y, fmaf(a, d10.y, g0.y));
        float t2 = fmaf(bb, d21.z, fmaf(a, d10.z, g0.z));
        float t3 = fmaf(bb, d21.w, fmaf(a, d10.w, g0.w));
        // softmax, exp2 domain; |t| <~ 8 so no max-subtraction needed in fp32
        float e0 = exp2f(t0), e1 = exp2f(t1), e2 = exp2f(t2), e3 = exp2f(t3);
        float s  = (e0 + e1) + (e2 + e3);
        float inv = __builtin_amdgcn_rcpf(s);  // 1-ulp rcp vs 1.9e-2 threshold
        float ec = (c == 0u) ? e0 : (c == 1u) ? e1 : (c == 2u) ? e2 : e3;
        r[j] = ec * inv;
        u += RATIO;
    }

    // two dwordx4 stores, 32 B contiguous per thread; wave = 2 KB monotone
    float4* dst = (float4*)(out + (size_t)gid * 8u);
    dst[0] = make_float4(r[0], r[1], r[2], r[3]);
    dst[1] = make_float4(r[4], r[5], r[6], r[7]);
}

extern "C" void kernel_launch(void* const* d_in, const int* in_sizes, int n_in,
                              void* d_out, int out_size, void* d_ws, size_t ws_size,
                              hipStream_t stream) {
    const float* x = (const float*)d_in[0];   // [1,32,14,14,14]
    const float* W = (const float*)d_in[1];   // [4,32]
    const float* b = (const float*)d_in[2];   // [4]
    float* out = (float*)d_out;               // [1,4,224,224,224]
    float4* z = (float4*)d_ws;                // 2744 float4 = 43,904 B scratch

    conv_small<<<(NSP + 255) / 256, 256, 0, stream>>>(x, W, b, z);
    store_stream<<<21952, 256, 0, stream>>>(z, out);
}

// Round 9
// 182.369 us; speedup vs baseline: 1.1985x; 1.1985x over previous
//
#include <hip/hip_runtime.h>
#include <hip/hip_bf16.h>

// Problem: x[1,32,14,14,14] -> trilinear upsample(224, align_corners) ->
// 1x1x1 conv (32->4) -> softmax(dim=1). Output [1,4,224,224,224] fp32.
//
// Optimization: conv (linear, per-voxel) commutes with interpolation (linear,
// weights sum to 1, bias passes through). So do the 32->4 contraction on the
// tiny 14^3 grid first, then upsample only 4 channels + fused softmax.
// The kernel is then pure-store-bandwidth bound (~180 MB out).
//
// R9 = R7/R8 resubmit (two consecutive container infra failures; kernel
// never ran). Ledger R0-R6: persistent blocks (null), full separability
// (null), NT stores (null/-), LDS-staged de-interleaved stores (-13 us),
// fill-shaped single-stream stores with redundant compute (-35 us). Every
// structural deviation from this kernel was neutral or negative; it is the
// empirical optimum (182.66 us measured as R0).

#define NSP 2744            // 14^3
#define NV  11239424        // 224^3
#define RATIO (13.0f / 223.0f)

// ---------------- Kernel 1: z[s][c] = W @ x + b on the 14^3 grid ------------
__global__ __launch_bounds__(256) void conv_small(
    const float* __restrict__ x,   // [32][2744]
    const float* __restrict__ W,   // [4][32]
    const float* __restrict__ b,   // [4]
    float4* __restrict__ z)        // [2744] (channels packed in float4)
{
    int s = blockIdx.x * 256 + threadIdx.x;
    if (s >= NSP) return;
    float a0 = b[0], a1 = b[1], a2 = b[2], a3 = b[3];
#pragma unroll
    for (int c = 0; c < 32; ++c) {
        float xv = x[c * NSP + s];
        a0 = fmaf(W[c],      xv, a0);
        a1 = fmaf(W[32 + c], xv, a1);
        a2 = fmaf(W[64 + c], xv, a2);
        a3 = fmaf(W[96 + c], xv, a3);
    }
    z[s] = make_float4(a0, a1, a2, a3);
}

// ---------------- Kernel 2: upsample + softmax ------------------------------
__device__ __forceinline__ float4 bilerp4(const float4* __restrict__ zs,
                                          int b00, int b01, int b10, int b11,
                                          int iw,
                                          float c00, float c01, float c10, float c11)
{
    float4 A = zs[b00 + iw], B = zs[b01 + iw], C = zs[b10 + iw], D = zs[b11 + iw];
    float4 r;
    r.x = fmaf(c11, D.x, fmaf(c10, C.x, fmaf(c01, B.x, c00 * A.x)));
    r.y = fmaf(c11, D.y, fmaf(c10, C.y, fmaf(c01, B.y, c00 * A.y)));
    r.z = fmaf(c11, D.z, fmaf(c10, C.z, fmaf(c01, B.z, c00 * A.z)));
    r.w = fmaf(c11, D.w, fmaf(c10, C.w, fmaf(c01, B.w, c00 * A.w)));
    return r;
}

__global__ __launch_bounds__(512) void upsample_softmax(
    const float4* __restrict__ z,   // [14][14][14] of float4 (4 channels)
    float* __restrict__ out)        // [4][224][224][224]
{
    __shared__ float4 zs[NSP];      // 43,904 B
    for (int k = threadIdx.x; k < NSP; k += 512) zs[k] = z[k];
    __syncthreads();

    // Each thread: 4 consecutive w voxels at one (d,h).
    // grid: 5488 blocks * 512 threads * 4 voxels = 224^3 exactly.
    unsigned gid = blockIdx.x * 512u + threadIdx.x;
    unsigned w4  = gid % 56u;        // 224/4 groups per row
    unsigned row = gid / 56u;        // d*224 + h
    unsigned hh  = row % 224u;
    unsigned dd  = row / 224u;

    float posd = (float)dd * RATIO;
    int   i0d  = min((int)posd, 12);
    float wd   = posd - (float)i0d;
    float posh = (float)hh * RATIO;
    int   i0h  = min((int)posh, 12);
    float wh   = posh - (float)i0h;

    int   wb    = (int)w4 * 4;
    float posw0 = (float)wb * RATIO;
    int   iw0   = min((int)posw0, 12);

    // bilinear (d,h) weights
    float c11 = wd * wh;
    float c10 = wd - c11;
    float c01 = wh - c11;
    float c00 = 1.0f - wd - wh + c11;

    int b00 = (i0d * 14 + i0h) * 14;
    int b01 = b00 + 14;
    int b10 = b00 + 196;
    int b11 = b00 + 210;

    // (d,h)-interpolated channel lines at the <=3 source w indices we need
    float4 g0 = bilerp4(zs, b00, b01, b10, b11, iw0,              c00, c01, c10, c11);
    float4 g1 = bilerp4(zs, b00, b01, b10, b11, iw0 + 1,          c00, c01, c10, c11);
    float4 g2 = bilerp4(zs, b00, b01, b10, b11, min(iw0 + 2, 13), c00, c01, c10, c11);

    float4 d10, d21;
    d10.x = g1.x - g0.x; d10.y = g1.y - g0.y; d10.z = g1.z - g0.z; d10.w = g1.w - g0.w;
    d21.x = g2.x - g1.x; d21.y = g2.y - g1.y; d21.z = g2.z - g1.z; d21.w = g2.w - g1.w;

    const float LOG2E = 1.44269504088896340736f;
    float4 res[4];
#pragma unroll
    for (int j = 0; j < 4; ++j) {
        float posw = (float)(wb + j) * RATIO;   // matches reference: pos = w * (13/223)
        int   i0w  = min((int)posw, 12);
        float ww   = posw - (float)i0w;
        bool  hi   = (i0w > iw0);
        float bx = hi ? g1.x : g0.x, by = hi ? g1.y : g0.y,
              bz = hi ? g1.z : g0.z, bw = hi ? g1.w : g0.w;
        float ex = hi ? d21.x : d10.x, ey = hi ? d21.y : d10.y,
              ez = hi ? d21.z : d10.z, ew = hi ? d21.w : d10.w;
        // logits
        float v0 = fmaf(ww, ex, bx);
        float v1 = fmaf(ww, ey, by);
        float v2 = fmaf(ww, ez, bz);
        float v3 = fmaf(ww, ew, bw);
        // softmax over 4 channels (|logits| ~ few units; exp2 safe w/o max-sub,
        // but subtract max for robustness -- cheap)
        float t0 = v0 * LOG2E, t1 = v1 * LOG2E, t2 = v2 * LOG2E, t3 = v3 * LOG2E;
        float m  = fmaxf(fmaxf(t0, t1), fmaxf(t2, t3));
        float e0 = exp2f(t0 - m), e1 = exp2f(t1 - m), e2 = exp2f(t2 - m), e3 = exp2f(t3 - m);
        float s  = (e0 + e1) + (e2 + e3);
        float inv = __builtin_amdgcn_rcpf(s);   // 1-ulp rcp, plenty for 1.9e-2 threshold
        res[j].x = e0 * inv;
        res[j].y = e1 * inv;
        res[j].z = e2 * inv;
        res[j].w = e3 * inv;
    }

    // transpose: gather per-channel float4 across the 4 voxels, coalesced stores
    unsigned sidx = row * 224u + (unsigned)wb;
    float4 o0 = make_float4(res[0].x, res[1].x, res[2].x, res[3].x);
    float4 o1 = make_float4(res[0].y, res[1].y, res[2].y, res[3].y);
    float4 o2 = make_float4(res[0].z, res[1].z, res[2].z, res[3].z);
    float4 o3 = make_float4(res[0].w, res[1].w, res[2].w, res[3].w);
    *(float4*)(out + 0u * NV + sidx) = o0;
    *(float4*)(out + 1u * NV + sidx) = o1;
    *(float4*)(out + 2u * NV + sidx) = o2;
    *(float4*)(out + 3u * NV + sidx) = o3;
}

extern "C" void kernel_launch(void* const* d_in, const int* in_sizes, int n_in,
                              void* d_out, int out_size, void* d_ws, size_t ws_size,
                              hipStream_t stream) {
    const float* x = (const float*)d_in[0];   // [1,32,14,14,14]
    const float* W = (const float*)d_in[1];   // [4,32]
    const float* b = (const float*)d_in[2];   // [4]
    float* out = (float*)d_out;               // [1,4,224,224,224]
    float4* z = (float4*)d_ws;                // 2744 float4 = 43,904 B scratch

    conv_small<<<(NSP + 255) / 256, 256, 0, stream>>>(x, W, b, z);
    upsample_softmax<<<(NV / 4) / 512, 512, 0, stream>>>(z, out);
}